// Round 2
// baseline (2047.042 us; speedup 1.0000x reference)
//
#include <hip/hip_runtime.h>
#include <hip/hip_bf16.h>
#include <cstdint>

typedef __hip_bfloat16 bf16;
#define CDIV(a,b) (((a)+(b)-1)/(b))

// ---------------- device helpers ----------------
__device__ __forceinline__ float lrelu02(float x) { return x > 0.f ? x : 0.2f * x; }

// monotone float<->int encoding for atomicMax on signed int
__device__ __forceinline__ int enc_f(float f) {
    int i = __float_as_int(f);
    return i >= 0 ? i : (i ^ 0x7FFFFFFF);
}
__device__ __forceinline__ float dec_i(int i) {
    return __int_as_float(i >= 0 ? i : (i ^ 0x7FFFFFFF));
}

__device__ __forceinline__ float toF(float x) { return x; }
__device__ __forceinline__ float toF(bf16 x) { return __bfloat162float(x); }
template<typename T> __device__ __forceinline__ T fromF(float x);
template<> __device__ __forceinline__ float fromF<float>(float x) { return x; }
template<> __device__ __forceinline__ bf16  fromF<bf16>(float x) { return __float2bfloat16(x); }

// ---------------- fill kernels ----------------
__global__ void fill_f32(float* __restrict__ p, float v, long n) {
    long i = (long)blockIdx.x * blockDim.x + threadIdx.x;
    long st = (long)gridDim.x * blockDim.x;
    for (; i < n; i += st) p[i] = v;
}
__global__ void fill_i32(int* __restrict__ p, int v, long n) {
    long i = (long)blockIdx.x * blockDim.x + threadIdx.x;
    long st = (long)gridDim.x * blockDim.x;
    for (; i < n; i += st) p[i] = v;
}

// ---------------- dense: Y[n,N] = gather(X)[n,K] @ W[K,N] + b ----------------
template<typename TI, typename TO, int K, int N, int R>
__global__ void __launch_bounds__(N) linear_kernel(
    const TI* __restrict__ X, const int* __restrict__ ids,
    const float* __restrict__ W, const float* __restrict__ bias,
    TO* __restrict__ Y, int n)
{
    __shared__ float xs[R * K];
    const int tid = threadIdx.x;
    const int base = blockIdx.x * R;

    for (int idx = tid; idx < R * K; idx += N) {
        int r = idx / K, k = idx - r * K;
        int row = base + r;
        float v = 0.f;
        if (row < n) {
            long sr = ids ? (long)ids[row] : (long)row;
            v = toF(X[sr * K + k]);
        }
        xs[idx] = v;
    }
    __syncthreads();

    float acc[R];
#pragma unroll
    for (int r = 0; r < R; ++r) acc[r] = 0.f;

    for (int k = 0; k < K; ++k) {
        float w = W[k * N + tid];
#pragma unroll
        for (int r = 0; r < R; ++r) acc[r] = fmaf(xs[r * K + k], w, acc[r]);
    }

    float bb = bias[tid];
#pragma unroll
    for (int r = 0; r < R; ++r) {
        int row = base + r;
        if (row < n) Y[(long)row * N + tid] = fromF<TO>(acc[r] + bb);
    }
}

// ---------------- edge pass A: logits + segment max ----------------
// one 64-lane group per edge; 4 heads x 64 channels, layout [n, h*64+c]
__global__ void edge_logits_kernel(
    const int* __restrict__ es, const int* __restrict__ ed,
    const bf16* __restrict__ xl, const bf16* __restrict__ xr,
    const float* __restrict__ ea, const float* __restrict__ We,
    const float* __restrict__ att,
    float* __restrict__ logit, int* __restrict__ mx, int E)
{
    const int lane = threadIdx.x & 63;
    const int e = blockIdx.x * (blockDim.x >> 6) + (threadIdx.x >> 6);
    if (e >= E) return;
    const int s = es[e], d = ed[e];
    const float a = ea[e];
    const bf16* __restrict__ xls = xl + (long)s * 256;
    const bf16* __restrict__ xrd = xr + (long)d * 256;

    float v[4];
#pragma unroll
    for (int h = 0; h < 4; ++h) {
        int c = h * 64 + lane;
        float t = lrelu02(toF(xls[c]) + toF(xrd[c]) + a * We[c]);
        v[h] = t * att[c];
    }
#pragma unroll
    for (int off = 32; off > 0; off >>= 1) {
#pragma unroll
        for (int h = 0; h < 4; ++h) v[h] += __shfl_down(v[h], off);
    }
    if (lane == 0) {
#pragma unroll
        for (int h = 0; h < 4; ++h) {
            logit[(long)e * 4 + h] = v[h];
            atomicMax(&mx[d * 4 + h], enc_f(v[h]));
        }
    }
}

// ---------------- edge pass B: exp + segment sum (ex overwrites logit) -----
__global__ void edge_exp_kernel(
    const int* __restrict__ ed, float* __restrict__ logit,
    const int* __restrict__ mx, float* __restrict__ den, int E4)
{
    int i = blockIdx.x * blockDim.x + threadIdx.x; // i = e*4 + h
    if (i >= E4) return;
    int e = i >> 2, h = i & 3;
    int d = ed[e];
    float m = dec_i(mx[d * 4 + h]);
    float v = expf(logit[i] - m);
    logit[i] = v;
    atomicAdd(&den[d * 4 + h], v);
}

// ---------------- edge pass C: alpha-weighted scatter ----------------
// dst range [dlo,dhi): out holds rows (d-dlo)
template<bool CONCAT>
__global__ void edge_scatter_kernel(
    const int* __restrict__ es, const int* __restrict__ ed,
    const bf16* __restrict__ xl,
    const float* __restrict__ ex, const float* __restrict__ den,
    float* __restrict__ out, int E, int dlo, int dhi)
{
    const int lane = threadIdx.x & 63;
    const int e = blockIdx.x * (blockDim.x >> 6) + (threadIdx.x >> 6);
    if (e >= E) return;
    const int d = ed[e];
    if (d < dlo || d >= dhi) return;
    const int s = es[e];
    float alpha[4];
#pragma unroll
    for (int h = 0; h < 4; ++h)
        alpha[h] = ex[(long)e * 4 + h] / (den[d * 4 + h] + 1e-16f);
    const bf16* __restrict__ xls = xl + (long)s * 256;
    if (CONCAT) {
#pragma unroll
        for (int h = 0; h < 4; ++h)
            atomicAdd(&out[(long)(d - dlo) * 256 + h * 64 + lane],
                      alpha[h] * toF(xls[h * 64 + lane]));
    } else {
        float t = 0.f;
#pragma unroll
        for (int h = 0; h < 4; ++h) t += alpha[h] * toF(xls[h * 64 + lane]);
        atomicAdd(&out[(long)(d - dlo) * 64 + lane], 0.25f * t);
    }
}

// ---------------- epilogue: bias + LN + leaky_relu ----------------
// x holds local rows (row - rlo); y written at global row index
template<int D, typename TO>
__global__ void __launch_bounds__(D) ln_act_kernel(
    const float* __restrict__ x, const float* __restrict__ bias,
    const float* __restrict__ g, const float* __restrict__ be,
    TO* __restrict__ y, int rlo, int rhi)
{
    const int row = rlo + blockIdx.x;
    const int t = threadIdx.x;
    if (row >= rhi) return;
    float v = x[(long)(row - rlo) * D + t] + bias[t];

    float s1 = v, s2 = v * v;
#pragma unroll
    for (int off = 32; off > 0; off >>= 1) {
        s1 += __shfl_down(s1, off);
        s2 += __shfl_down(s2, off);
    }
    __shared__ float ws1[D / 64 > 0 ? D / 64 : 1], ws2[D / 64 > 0 ? D / 64 : 1];
    int wid = t >> 6;
    if ((t & 63) == 0) { ws1[wid] = s1; ws2[wid] = s2; }
    __syncthreads();
    float sum = 0.f, ssq = 0.f;
#pragma unroll
    for (int w = 0; w < D / 64; ++w) { sum += ws1[w]; ssq += ws2[w]; }

    const float inv = 1.f / (float)D;
    float m = sum * inv;
    float var = ssq * inv - m * m;
    float r = rsqrtf(var + 1e-5f);
    float o = g[t] * (v - m) * r + be[t];
    y[(long)row * D + t] = fromF<TO>(lrelu02(o));
}

// ---------------- host orchestration ----------------
extern "C" void kernel_launch(void* const* d_in, const int* in_sizes, int n_in,
                              void* d_out, int out_size, void* d_ws, size_t ws_size,
                              hipStream_t stream)
{
    auto F = [&](int i) { return (const float*)d_in[i]; };
    auto I = [&](int i) { return (const int*)d_in[i]; };

    const int NU = in_sizes[0];
    const int NM = in_sizes[1];
    const int E  = in_sizes[2] / 2;

    const int* user_ids  = I(0);
    const int* movie_ids = I(1);
    const int* ei_um = I(2);          // [0:E]=src users, [E:2E]=dst movies
    const int* ei_mu = I(3);          // [0:E]=src movies, [E:2E]=dst users
    const float* ea_um = F(4);
    const float* ea_mu = F(5);
    const float* user_emb  = F(6);
    const float* movie_emb = F(7);
    const float* W_user = F(8),  *b_user = F(9);
    const float* W_movie = F(10), *b_movie = F(11);
    const int L0UM = 12, L0MU = 19, L1UM = 26, L1MU = 33;
    const float* g0u = F(40), *be0u = F(41);
    const float* g0m = F(42), *be0m = F(43);
    const float* g1u = F(44), *be1u = F(45);
    const float* g1m = F(46), *be1m = F(47);

    // ---- workspace layout (explicit lifetimes, ~192 MB total) ----
    const int CH = (NU + 1) / 2;                         // user row chunk
    const size_t accElems = (size_t)CH * 256;            // 12.8M f32 (51.2 MB)
    char* w = (char*)d_ws;
    float* ACC = (float*)w;                              // f32 scratch region
    size_t off = accElems * sizeof(float);
    bf16* UB1 = (bf16*)(w + off); off += (size_t)NU * 256 * sizeof(bf16);
    bf16* UB2 = (bf16*)(w + off); off += (size_t)NU * 256 * sizeof(bf16);
    bf16* MB1 = (bf16*)(w + off); off += (size_t)NM * 256 * sizeof(bf16);
    bf16* MB2 = (bf16*)(w + off); off += (size_t)NM * 256 * sizeof(bf16);
    bf16* MB3 = (bf16*)(w + off); off += (size_t)NM * 256 * sizeof(bf16);
    float* elog = (float*)(w + off); off += (size_t)E * 4 * sizeof(float);
    int*   mx   = (int*)(w + off);   off += (size_t)NU * 4 * sizeof(int);
    float* den  = (float*)(w + off); off += (size_t)NU * 4 * sizeof(float);
    if (off > ws_size) return;   // guard: workspace too small -> clean fail

    // phase-0 activations live inside ACC (dead before ACC's first accum use)
    float* xu0 = ACC;                                    // [NU,64]
    float* xm0 = ACC + (size_t)NU * 64;                  // [NM,64]

    float* out_u = (float*)d_out;                        // xu2 [NU,64]
    float* out_m = out_u + (size_t)NU * 64;              // xm2 [NM,64]

    const int FB = 256;
    auto fg = [&](long n) { long b = CDIV(n, FB); if (b > 8192) b = 8192; return dim3((unsigned)b); };
    dim3 eb(256);
    dim3 eg(CDIV(E, 4));
    dim3 eg4(CDIV(E * 4, 256));

    // ---- phase 0: embedding gathers + input projections (f32) ----
    linear_kernel<float, float, 64, 64, 8><<<CDIV(NU, 8), 64, 0, stream>>>(user_emb, user_ids, W_user, b_user, xu0, NU);
    linear_kernel<float, float, 64, 64, 8><<<CDIV(NM, 8), 64, 0, stream>>>(movie_emb, movie_ids, W_movie, b_movie, xm0, NM);

    // ---- layer-0 projections (f32 in -> bf16 out), all before edge passes ----
    linear_kernel<float, bf16, 64, 256, 8><<<CDIV(NU, 8), 256, 0, stream>>>(xu0, nullptr, F(L0UM+0), F(L0UM+1), UB1, NU); // xl_u0
    linear_kernel<float, bf16, 64, 256, 8><<<CDIV(NM, 8), 256, 0, stream>>>(xm0, nullptr, F(L0UM+2), F(L0UM+3), MB1, NM); // xr_m0
    linear_kernel<float, bf16, 64, 256, 8><<<CDIV(NM, 8), 256, 0, stream>>>(xm0, nullptr, F(L0MU+0), F(L0MU+1), MB3, NM); // xl_m0
    linear_kernel<float, bf16, 64, 256, 8><<<CDIV(NU, 8), 256, 0, stream>>>(xu0, nullptr, F(L0MU+2), F(L0MU+3), UB2, NU); // xr_u0
    // xu0/xm0 now dead -> ACC free

    // ================= layer 0, um (dst = movies) -> xm1 in MB2 =================
    fill_i32<<<fg((long)NM*4), FB, 0, stream>>>(mx, INT_MIN, (long)NM * 4);
    fill_f32<<<fg((long)NM*4), FB, 0, stream>>>(den, 0.f, (long)NM * 4);
    edge_logits_kernel<<<eg, eb, 0, stream>>>(ei_um, ei_um + E, UB1, MB1, ea_um, F(L0UM+4), F(L0UM+5), elog, mx, E);
    edge_exp_kernel<<<eg4, eb, 0, stream>>>(ei_um + E, elog, mx, den, E * 4);
    fill_f32<<<fg((long)NM*256), FB, 0, stream>>>(ACC, 0.f, (long)NM * 256);
    edge_scatter_kernel<true><<<eg, eb, 0, stream>>>(ei_um, ei_um + E, UB1, elog, den, ACC, E, 0, NM);
    ln_act_kernel<256, bf16><<<NM, 256, 0, stream>>>(ACC, F(L0UM+6), g0m, be0m, MB2, 0, NM);
    // UB1, MB1 dead

    // ================= layer 0, mu (dst = users) -> xu1 in UB2 =================
    fill_i32<<<fg((long)NU*4), FB, 0, stream>>>(mx, INT_MIN, (long)NU * 4);
    fill_f32<<<fg((long)NU*4), FB, 0, stream>>>(den, 0.f, (long)NU * 4);
    edge_logits_kernel<<<eg, eb, 0, stream>>>(ei_mu, ei_mu + E, MB3, UB2, ea_mu, F(L0MU+4), F(L0MU+5), elog, mx, E);
    edge_exp_kernel<<<eg4, eb, 0, stream>>>(ei_mu + E, elog, mx, den, E * 4);
    for (int c = 0; c < 2; ++c) {
        int lo = c * CH, hi = (c == 0) ? CH : NU;
        long rows = hi - lo;
        fill_f32<<<fg(rows * 256), FB, 0, stream>>>(ACC, 0.f, rows * 256);
        edge_scatter_kernel<true><<<eg, eb, 0, stream>>>(ei_mu, ei_mu + E, MB3, elog, den, ACC, E, lo, hi);
        ln_act_kernel<256, bf16><<<(unsigned)rows, 256, 0, stream>>>(ACC, F(L0MU+6), g0u, be0u, UB2, lo, hi);
    }
    // MB3 dead; UB2 = xu1 (bf16)

    // ================= layer 1, um (dst = movies) -> out_m =================
    linear_kernel<bf16, bf16, 256, 256, 8><<<CDIV(NU, 8), 256, 0, stream>>>(UB2, nullptr, F(L1UM+0), F(L1UM+1), UB1, NU); // xl_u1
    linear_kernel<bf16, bf16, 256, 256, 8><<<CDIV(NM, 8), 256, 0, stream>>>(MB2, nullptr, F(L1UM+2), F(L1UM+3), MB1, NM); // xr_m1
    fill_i32<<<fg((long)NM*4), FB, 0, stream>>>(mx, INT_MIN, (long)NM * 4);
    fill_f32<<<fg((long)NM*4), FB, 0, stream>>>(den, 0.f, (long)NM * 4);
    edge_logits_kernel<<<eg, eb, 0, stream>>>(ei_um, ei_um + E, UB1, MB1, ea_um, F(L1UM+4), F(L1UM+5), elog, mx, E);
    edge_exp_kernel<<<eg4, eb, 0, stream>>>(ei_um + E, elog, mx, den, E * 4);
    fill_f32<<<fg((long)NM*64), FB, 0, stream>>>(out_m, 0.f, (long)NM * 64);
    edge_scatter_kernel<false><<<eg, eb, 0, stream>>>(ei_um, ei_um + E, UB1, elog, den, out_m, E, 0, NM);
    ln_act_kernel<64, float><<<NM, 64, 0, stream>>>(out_m, F(L1UM+6), g1m, be1m, out_m, 0, NM);

    // ================= layer 1, mu (dst = users) -> out_u =================
    linear_kernel<bf16, bf16, 256, 256, 8><<<CDIV(NM, 8), 256, 0, stream>>>(MB2, nullptr, F(L1MU+0), F(L1MU+1), MB3, NM); // xl_m1
    linear_kernel<bf16, bf16, 256, 256, 8><<<CDIV(NU, 8), 256, 0, stream>>>(UB2, nullptr, F(L1MU+2), F(L1MU+3), UB1, NU); // xr_u1
    fill_i32<<<fg((long)NU*4), FB, 0, stream>>>(mx, INT_MIN, (long)NU * 4);
    fill_f32<<<fg((long)NU*4), FB, 0, stream>>>(den, 0.f, (long)NU * 4);
    edge_logits_kernel<<<eg, eb, 0, stream>>>(ei_mu, ei_mu + E, MB3, UB1, ea_mu, F(L1MU+4), F(L1MU+5), elog, mx, E);
    edge_exp_kernel<<<eg4, eb, 0, stream>>>(ei_mu + E, elog, mx, den, E * 4);
    fill_f32<<<fg((long)NU*64), FB, 0, stream>>>(out_u, 0.f, (long)NU * 64);
    edge_scatter_kernel<false><<<eg, eb, 0, stream>>>(ei_mu, ei_mu + E, MB3, elog, den, out_u, E, 0, NU);
    ln_act_kernel<64, float><<<NU, 64, 0, stream>>>(out_u, F(L1MU+6), g1u, be1u, out_u, 0, NU);
}

// Round 3
// 1480.290 us; speedup vs baseline: 1.3829x; 1.3829x over previous
//
#include <hip/hip_runtime.h>
#include <hip/hip_bf16.h>
#include <cstdint>

typedef __hip_bfloat16 bf16;
#define CDIV(a,b) (((a)+(b)-1)/(b))

typedef __attribute__((ext_vector_type(8))) short short8;
typedef __attribute__((ext_vector_type(8))) unsigned short usht8;
typedef __attribute__((ext_vector_type(4))) float f32x4v;

// ---------------- device helpers ----------------
__device__ __forceinline__ float lrelu02(float x) { return x > 0.f ? x : 0.2f * x; }

__device__ __forceinline__ int enc_f(float f) {
    int i = __float_as_int(f);
    return i >= 0 ? i : (i ^ 0x7FFFFFFF);
}
__device__ __forceinline__ float dec_i(int i) {
    return __int_as_float(i >= 0 ? i : (i ^ 0x7FFFFFFF));
}

__device__ __forceinline__ float toF(float x) { return x; }
__device__ __forceinline__ float toF(bf16 x) { return __bfloat162float(x); }
template<typename T> __device__ __forceinline__ T fromF(float x);
template<> __device__ __forceinline__ float fromF<float>(float x) { return x; }
template<> __device__ __forceinline__ bf16  fromF<bf16>(float x) { return __float2bfloat16(x); }

// f32 -> bf16 bits, round-to-nearest-even
__device__ __forceinline__ unsigned short f2b(float f) {
    unsigned u = __float_as_uint(f);
    unsigned r = u + 0x7FFFu + ((u >> 16) & 1u);
    return (unsigned short)(r >> 16);
}

// swizzled LDS index (ushort units) for [row][32] tiles, 8-elem granularity:
// spreads the 16-lane fragment reads across all 8 bank-groups
__device__ __forceinline__ int swz(int row, int kg) {
    return row * 32 + (kg ^ ((row >> 1) & 3)) * 8;
}

// ---------------- fill kernels ----------------
__global__ void fill_f32(float* __restrict__ p, float v, long n) {
    long i = (long)blockIdx.x * blockDim.x + threadIdx.x;
    long st = (long)gridDim.x * blockDim.x;
    for (; i < n; i += st) p[i] = v;
}
__global__ void fill_i32(int* __restrict__ p, int v, long n) {
    long i = (long)blockIdx.x * blockDim.x + threadIdx.x;
    long st = (long)gridDim.x * blockDim.x;
    for (; i < n; i += st) p[i] = v;
}

// ---------------- weight transpose+convert: W[K][N] f32 -> Wt[N][K] bf16 ----
struct TxArgs {
    const float* src[10];
    unsigned short* dst[10];
    int K[10];
    int N[10];
};
__global__ void txp_kernel(TxArgs a) {
    const int m = blockIdx.y;
    const int K = a.K[m], N = a.N[m];
    const long total = (long)K * N;
    const float* __restrict__ s = a.src[m];
    unsigned short* __restrict__ d = a.dst[m];
    for (long i = (long)blockIdx.x * blockDim.x + threadIdx.x; i < total;
         i += (long)gridDim.x * blockDim.x) {
        int k = (int)(i / N), nn = (int)(i - (long)k * N);
        d[(long)nn * K + k] = f2b(s[i]);
    }
}

// ---------------- MFMA GEMM: Y[n,N](bf16) = A[n,K] @ W[K,N] + bias ----------
// block: 64 rows x N cols, 256 threads (4 waves), wave w owns cols [w*N/4, ...)
// A: bf16 [n,K] (GATHER=false) or f32 table + ids (GATHER=true)
// Wt: bf16 [N][K] (pre-transposed)
template<int K, int N, bool GATHER>
__global__ void __launch_bounds__(256) gemm_kernel(
    const void* __restrict__ Asrc, const int* __restrict__ ids,
    const unsigned short* __restrict__ Wt, const float* __restrict__ bias,
    unsigned short* __restrict__ Y, int n)
{
    constexpr int NCT = N / 64;      // 16-col tiles per wave
    const int t = threadIdx.x;
    const int wid = t >> 6, lane = t & 63;
    const int row0 = blockIdx.x * 64;

    __shared__ unsigned short As[64 * 32];
    __shared__ unsigned short Ws[N * 32];

    f32x4v acc[4][NCT];
#pragma unroll
    for (int rt = 0; rt < 4; ++rt)
#pragma unroll
        for (int ct = 0; ct < NCT; ++ct) acc[rt][ct] = (f32x4v){0.f, 0.f, 0.f, 0.f};

    const int r_st = t >> 2, kg_st = t & 3;    // A staging: (row, k-group)
    const int grow = row0 + r_st;
    long abase = 0;
    if (grow < n) abase = GATHER ? (long)ids[grow] * K : (long)grow * K;

    for (int kt = 0; kt < K / 32; ++kt) {
        // ---- stage A tile (64x32 bf16) ----
        usht8 av = (usht8)0;
        if (grow < n) {
            if (GATHER) {
                const float* p = (const float*)Asrc + abase + kt * 32 + kg_st * 8;
#pragma unroll
                for (int j = 0; j < 8; ++j) av[j] = f2b(p[j]);
            } else {
                av = *(const usht8*)((const unsigned short*)Asrc + abase + kt * 32 + kg_st * 8);
            }
        }
        *(usht8*)&As[swz(r_st, kg_st)] = av;
        // ---- stage W tile (N x 32 bf16, fragment-major) ----
#pragma unroll
        for (int i = 0; i < NCT; ++i) {
            int idx = t + i * 256;
            int c = idx >> 2, kg = idx & 3;
            *(usht8*)&Ws[swz(c, kg)] = *(const usht8*)&Wt[(long)c * K + kt * 32 + kg * 8];
        }
        __syncthreads();

        const int kgrp = lane >> 4;
        short8 af[4];
#pragma unroll
        for (int rt = 0; rt < 4; ++rt)
            af[rt] = *(const short8*)&As[swz(rt * 16 + (lane & 15), kgrp)];
#pragma unroll
        for (int ct = 0; ct < NCT; ++ct) {
            int col = wid * (N / 4) + ct * 16 + (lane & 15);
            short8 bfr = *(const short8*)&Ws[swz(col, kgrp)];
#pragma unroll
            for (int rt = 0; rt < 4; ++rt)
                acc[rt][ct] = __builtin_amdgcn_mfma_f32_16x16x32_bf16(af[rt], bfr, acc[rt][ct], 0, 0, 0);
        }
        __syncthreads();
    }

    // ---- epilogue: + bias, store bf16 ----
#pragma unroll
    for (int ct = 0; ct < NCT; ++ct) {
        int col = wid * (N / 4) + ct * 16 + (lane & 15);
        float bb = bias[col];
#pragma unroll
        for (int rt = 0; rt < 4; ++rt) {
#pragma unroll
            for (int j = 0; j < 4; ++j) {
                int row = row0 + rt * 16 + (lane >> 4) * 4 + j;
                if (row < n) Y[(long)row * N + col] = f2b(acc[rt][ct][j] + bb);
            }
        }
    }
}

// ---------------- edge pass A: logits + segment max ----------------
__global__ void edge_logits_kernel(
    const int* __restrict__ es, const int* __restrict__ ed,
    const bf16* __restrict__ xl, const bf16* __restrict__ xr,
    const float* __restrict__ ea, const float* __restrict__ We,
    const float* __restrict__ att,
    float* __restrict__ logit, int* __restrict__ mx, int E)
{
    const int lane = threadIdx.x & 63;
    const int e = blockIdx.x * (blockDim.x >> 6) + (threadIdx.x >> 6);
    if (e >= E) return;
    const int s = es[e], d = ed[e];
    const float a = ea[e];
    const bf16* __restrict__ xls = xl + (long)s * 256;
    const bf16* __restrict__ xrd = xr + (long)d * 256;

    float v[4];
#pragma unroll
    for (int h = 0; h < 4; ++h) {
        int c = h * 64 + lane;
        float t = lrelu02(toF(xls[c]) + toF(xrd[c]) + a * We[c]);
        v[h] = t * att[c];
    }
#pragma unroll
    for (int off = 32; off > 0; off >>= 1) {
#pragma unroll
        for (int h = 0; h < 4; ++h) v[h] += __shfl_down(v[h], off);
    }
    if (lane == 0) {
#pragma unroll
        for (int h = 0; h < 4; ++h) {
            logit[(long)e * 4 + h] = v[h];
            atomicMax(&mx[d * 4 + h], enc_f(v[h]));
        }
    }
}

// ---------------- edge pass B: exp + segment sum (in place) ----------------
__global__ void edge_exp_kernel(
    const int* __restrict__ ed, float* __restrict__ logit,
    const int* __restrict__ mx, float* __restrict__ den, int E4)
{
    int i = blockIdx.x * blockDim.x + threadIdx.x; // i = e*4 + h
    if (i >= E4) return;
    int e = i >> 2, h = i & 3;
    int d = ed[e];
    float m = dec_i(mx[d * 4 + h]);
    float v = expf(logit[i] - m);
    logit[i] = v;
    atomicAdd(&den[d * 4 + h], v);
}

// ---------------- edge pass C: alpha-weighted scatter ----------------
template<bool CONCAT>
__global__ void edge_scatter_kernel(
    const int* __restrict__ es, const int* __restrict__ ed,
    const bf16* __restrict__ xl,
    const float* __restrict__ ex, const float* __restrict__ den,
    float* __restrict__ out, int E, int dlo, int dhi)
{
    const int lane = threadIdx.x & 63;
    const int e = blockIdx.x * (blockDim.x >> 6) + (threadIdx.x >> 6);
    if (e >= E) return;
    const int d = ed[e];
    if (d < dlo || d >= dhi) return;
    const int s = es[e];
    float alpha[4];
#pragma unroll
    for (int h = 0; h < 4; ++h)
        alpha[h] = ex[(long)e * 4 + h] / (den[d * 4 + h] + 1e-16f);
    const bf16* __restrict__ xls = xl + (long)s * 256;
    if (CONCAT) {
#pragma unroll
        for (int h = 0; h < 4; ++h)
            atomicAdd(&out[(long)(d - dlo) * 256 + h * 64 + lane],
                      alpha[h] * toF(xls[h * 64 + lane]));
    } else {
        float t = 0.f;
#pragma unroll
        for (int h = 0; h < 4; ++h) t += alpha[h] * toF(xls[h * 64 + lane]);
        atomicAdd(&out[(long)(d - dlo) * 64 + lane], 0.25f * t);
    }
}

// ---------------- epilogue: bias + LN + leaky_relu ----------------
template<int D, typename TO>
__global__ void __launch_bounds__(D) ln_act_kernel(
    const float* __restrict__ x, const float* __restrict__ bias,
    const float* __restrict__ g, const float* __restrict__ be,
    TO* __restrict__ y, int rlo, int rhi)
{
    const int row = rlo + blockIdx.x;
    const int t = threadIdx.x;
    if (row >= rhi) return;
    float v = x[(long)(row - rlo) * D + t] + bias[t];

    float s1 = v, s2 = v * v;
#pragma unroll
    for (int off = 32; off > 0; off >>= 1) {
        s1 += __shfl_down(s1, off);
        s2 += __shfl_down(s2, off);
    }
    __shared__ float ws1[D / 64 > 0 ? D / 64 : 1], ws2[D / 64 > 0 ? D / 64 : 1];
    int wid = t >> 6;
    if ((t & 63) == 0) { ws1[wid] = s1; ws2[wid] = s2; }
    __syncthreads();
    float sum = 0.f, ssq = 0.f;
#pragma unroll
    for (int w = 0; w < D / 64; ++w) { sum += ws1[w]; ssq += ws2[w]; }

    const float inv = 1.f / (float)D;
    float m = sum * inv;
    float var = ssq * inv - m * m;
    float r = rsqrtf(var + 1e-5f);
    float o = g[t] * (v - m) * r + be[t];
    y[(long)row * D + t] = fromF<TO>(lrelu02(o));
}

// ---------------- host orchestration ----------------
extern "C" void kernel_launch(void* const* d_in, const int* in_sizes, int n_in,
                              void* d_out, int out_size, void* d_ws, size_t ws_size,
                              hipStream_t stream)
{
    auto F = [&](int i) { return (const float*)d_in[i]; };
    auto I = [&](int i) { return (const int*)d_in[i]; };

    const int NU = in_sizes[0];
    const int NM = in_sizes[1];
    const int E  = in_sizes[2] / 2;

    const int* user_ids  = I(0);
    const int* movie_ids = I(1);
    const int* ei_um = I(2);
    const int* ei_mu = I(3);
    const float* ea_um = F(4);
    const float* ea_mu = F(5);
    const float* user_emb  = F(6);
    const float* movie_emb = F(7);
    const float* W_user = F(8),  *b_user = F(9);
    const float* W_movie = F(10), *b_movie = F(11);
    const int L0UM = 12, L0MU = 19, L1UM = 26, L1MU = 33;
    const float* g0u = F(40), *be0u = F(41);
    const float* g0m = F(42), *be0m = F(43);
    const float* g1u = F(44), *be1u = F(45);
    const float* g1m = F(46), *be1m = F(47);

    // ---- workspace layout ----
    const int CH = (NU + 1) / 2;
    const size_t accElems = (size_t)CH * 256;            // 51.2 MB f32 scratch
    char* w = (char*)d_ws;
    float* ACC = (float*)w;
    size_t off = accElems * sizeof(float);
    bf16* UB1 = (bf16*)(w + off); off += (size_t)NU * 256 * sizeof(bf16);
    bf16* UB2 = (bf16*)(w + off); off += (size_t)NU * 256 * sizeof(bf16);
    bf16* MB1 = (bf16*)(w + off); off += (size_t)NM * 256 * sizeof(bf16);
    bf16* MB2 = (bf16*)(w + off); off += (size_t)NM * 256 * sizeof(bf16);
    bf16* MB3 = (bf16*)(w + off); off += (size_t)NM * 256 * sizeof(bf16);
    float* elog = (float*)(w + off); off += (size_t)E * 4 * sizeof(float);
    int*   mx   = (int*)(w + off);   off += (size_t)NU * 4 * sizeof(int);
    float* den  = (float*)(w + off); off += (size_t)NU * 4 * sizeof(float);
    // bf16 transposed weights
    unsigned short* wtp = (unsigned short*)(w + off);
    unsigned short* wt_user  = wtp;            wtp += 64 * 64;
    unsigned short* wt_movie = wtp;            wtp += 64 * 64;
    unsigned short* wt_l0um_l = wtp;           wtp += 64 * 256;
    unsigned short* wt_l0um_r = wtp;           wtp += 64 * 256;
    unsigned short* wt_l0mu_l = wtp;           wtp += 64 * 256;
    unsigned short* wt_l0mu_r = wtp;           wtp += 64 * 256;
    unsigned short* wt_l1um_l = wtp;           wtp += 256 * 256;
    unsigned short* wt_l1um_r = wtp;           wtp += 256 * 256;
    unsigned short* wt_l1mu_l = wtp;           wtp += 256 * 256;
    unsigned short* wt_l1mu_r = wtp;           wtp += 256 * 256;
    off += (size_t)((char*)wtp - (char*)(w + off));
    if (off > ws_size) return;

    // phase-0 activations (bf16) live inside ACC (dead before ACC's accum use)
    unsigned short* xu0b = (unsigned short*)ACC;                 // [NU,64]
    unsigned short* xm0b = xu0b + (size_t)NU * 64;               // [NM,64]

    float* out_u = (float*)d_out;
    float* out_m = out_u + (size_t)NU * 64;

    const int FB = 256;
    auto fg = [&](long n) { long b = CDIV(n, FB); if (b > 8192) b = 8192; return dim3((unsigned)b); };
    dim3 eb(256);
    dim3 eg(CDIV(E, 4));
    dim3 eg4(CDIV(E * 4, 256));

    // ---- weight conversion (f32 [K][N] -> bf16 [N][K]) ----
    TxArgs tx;
    const float* srcs[10] = {W_user, W_movie, F(L0UM+0), F(L0UM+2), F(L0MU+0), F(L0MU+2),
                             F(L1UM+0), F(L1UM+2), F(L1MU+0), F(L1MU+2)};
    unsigned short* dsts[10] = {wt_user, wt_movie, wt_l0um_l, wt_l0um_r, wt_l0mu_l, wt_l0mu_r,
                                wt_l1um_l, wt_l1um_r, wt_l1mu_l, wt_l1mu_r};
    int Ks[10] = {64, 64, 64, 64, 64, 64, 256, 256, 256, 256};
    int Ns[10] = {64, 64, 256, 256, 256, 256, 256, 256, 256, 256};
    for (int i = 0; i < 10; ++i) { tx.src[i] = srcs[i]; tx.dst[i] = dsts[i]; tx.K[i] = Ks[i]; tx.N[i] = Ns[i]; }
    txp_kernel<<<dim3(64, 10), 256, 0, stream>>>(tx);

    // ---- phase 0: embedding gather + input projection (MFMA) ----
    gemm_kernel<64, 64, true><<<CDIV(NU, 64), 256, 0, stream>>>(user_emb, user_ids, wt_user, b_user, xu0b, NU);
    gemm_kernel<64, 64, true><<<CDIV(NM, 64), 256, 0, stream>>>(movie_emb, movie_ids, wt_movie, b_movie, xm0b, NM);

    // ---- layer-0 projections ----
    gemm_kernel<64, 256, false><<<CDIV(NU, 64), 256, 0, stream>>>(xu0b, nullptr, wt_l0um_l, F(L0UM+1), (unsigned short*)UB1, NU); // xl_u0
    gemm_kernel<64, 256, false><<<CDIV(NM, 64), 256, 0, stream>>>(xm0b, nullptr, wt_l0um_r, F(L0UM+3), (unsigned short*)MB1, NM); // xr_m0
    gemm_kernel<64, 256, false><<<CDIV(NM, 64), 256, 0, stream>>>(xm0b, nullptr, wt_l0mu_l, F(L0MU+1), (unsigned short*)MB3, NM); // xl_m0
    gemm_kernel<64, 256, false><<<CDIV(NU, 64), 256, 0, stream>>>(xu0b, nullptr, wt_l0mu_r, F(L0MU+3), (unsigned short*)UB2, NU); // xr_u0
    // xu0b/xm0b dead -> ACC free

    // ================= layer 0, um (dst = movies) -> xm1 in MB2 =================
    fill_i32<<<fg((long)NM*4), FB, 0, stream>>>(mx, INT_MIN, (long)NM * 4);
    fill_f32<<<fg((long)NM*4), FB, 0, stream>>>(den, 0.f, (long)NM * 4);
    edge_logits_kernel<<<eg, eb, 0, stream>>>(ei_um, ei_um + E, UB1, MB1, ea_um, F(L0UM+4), F(L0UM+5), elog, mx, E);
    edge_exp_kernel<<<eg4, eb, 0, stream>>>(ei_um + E, elog, mx, den, E * 4);
    fill_f32<<<fg((long)NM*256), FB, 0, stream>>>(ACC, 0.f, (long)NM * 256);
    edge_scatter_kernel<true><<<eg, eb, 0, stream>>>(ei_um, ei_um + E, UB1, elog, den, ACC, E, 0, NM);
    ln_act_kernel<256, bf16><<<NM, 256, 0, stream>>>(ACC, F(L0UM+6), g0m, be0m, MB2, 0, NM);
    // UB1, MB1 dead

    // ================= layer 0, mu (dst = users) -> xu1 in UB2 =================
    fill_i32<<<fg((long)NU*4), FB, 0, stream>>>(mx, INT_MIN, (long)NU * 4);
    fill_f32<<<fg((long)NU*4), FB, 0, stream>>>(den, 0.f, (long)NU * 4);
    edge_logits_kernel<<<eg, eb, 0, stream>>>(ei_mu, ei_mu + E, MB3, UB2, ea_mu, F(L0MU+4), F(L0MU+5), elog, mx, E);
    edge_exp_kernel<<<eg4, eb, 0, stream>>>(ei_mu + E, elog, mx, den, E * 4);
    for (int c = 0; c < 2; ++c) {
        int lo = c * CH, hi = (c == 0) ? CH : NU;
        long rows = hi - lo;
        fill_f32<<<fg(rows * 256), FB, 0, stream>>>(ACC, 0.f, rows * 256);
        edge_scatter_kernel<true><<<eg, eb, 0, stream>>>(ei_mu, ei_mu + E, MB3, elog, den, ACC, E, lo, hi);
        ln_act_kernel<256, bf16><<<(unsigned)rows, 256, 0, stream>>>(ACC, F(L0MU+6), g0u, be0u, UB2, lo, hi);
    }
    // MB3 dead; UB2 = xu1

    // ================= layer 1, um (dst = movies) -> out_m =================
    gemm_kernel<256, 256, false><<<CDIV(NU, 64), 256, 0, stream>>>((unsigned short*)UB2, nullptr, wt_l1um_l, F(L1UM+1), (unsigned short*)UB1, NU); // xl_u1
    gemm_kernel<256, 256, false><<<CDIV(NM, 64), 256, 0, stream>>>((unsigned short*)MB2, nullptr, wt_l1um_r, F(L1UM+3), (unsigned short*)MB1, NM); // xr_m1
    fill_i32<<<fg((long)NM*4), FB, 0, stream>>>(mx, INT_MIN, (long)NM * 4);
    fill_f32<<<fg((long)NM*4), FB, 0, stream>>>(den, 0.f, (long)NM * 4);
    edge_logits_kernel<<<eg, eb, 0, stream>>>(ei_um, ei_um + E, UB1, MB1, ea_um, F(L1UM+4), F(L1UM+5), elog, mx, E);
    edge_exp_kernel<<<eg4, eb, 0, stream>>>(ei_um + E, elog, mx, den, E * 4);
    fill_f32<<<fg((long)NM*64), FB, 0, stream>>>(out_m, 0.f, (long)NM * 64);
    edge_scatter_kernel<false><<<eg, eb, 0, stream>>>(ei_um, ei_um + E, UB1, elog, den, out_m, E, 0, NM);
    ln_act_kernel<64, float><<<NM, 64, 0, stream>>>(out_m, F(L1UM+6), g1m, be1m, out_m, 0, NM);

    // ================= layer 1, mu (dst = users) -> out_u =================
    gemm_kernel<256, 256, false><<<CDIV(NM, 64), 256, 0, stream>>>((unsigned short*)MB2, nullptr, wt_l1mu_l, F(L1MU+1), (unsigned short*)MB3, NM); // xl_m1
    gemm_kernel<256, 256, false><<<CDIV(NU, 64), 256, 0, stream>>>((unsigned short*)UB2, nullptr, wt_l1mu_r, F(L1MU+3), (unsigned short*)UB1, NU); // xr_u1
    fill_i32<<<fg((long)NU*4), FB, 0, stream>>>(mx, INT_MIN, (long)NU * 4);
    fill_f32<<<fg((long)NU*4), FB, 0, stream>>>(den, 0.f, (long)NU * 4);
    edge_logits_kernel<<<eg, eb, 0, stream>>>(ei_mu, ei_mu + E, MB3, UB1, ea_mu, F(L1MU+4), F(L1MU+5), elog, mx, E);
    edge_exp_kernel<<<eg4, eb, 0, stream>>>(ei_mu + E, elog, mx, den, E * 4);
    fill_f32<<<fg((long)NU*64), FB, 0, stream>>>(out_u, 0.f, (long)NU * 64);
    edge_scatter_kernel<false><<<eg, eb, 0, stream>>>(ei_mu, ei_mu + E, MB3, elog, den, out_u, E, 0, NU);
    ln_act_kernel<64, float><<<NU, 64, 0, stream>>>(out_u, F(L1MU+6), g1u, be1u, out_u, 0, NU);
}

// Round 4
// 751.750 us; speedup vs baseline: 2.7230x; 1.9691x over previous
//
#include <hip/hip_runtime.h>
#include <hip/hip_bf16.h>
#include <cstdint>

typedef __hip_bfloat16 bf16;
#define CDIV(a,b) (((a)+(b)-1)/(b))

typedef __attribute__((ext_vector_type(8))) short short8;
typedef __attribute__((ext_vector_type(8))) unsigned short usht8;
typedef __attribute__((ext_vector_type(4))) float f32x4v;

// ---------------- device helpers ----------------
__device__ __forceinline__ float lrelu02(float x) { return x > 0.f ? x : 0.2f * x; }

__device__ __forceinline__ float toF(float x) { return x; }
__device__ __forceinline__ float toF(bf16 x) { return __bfloat162float(x); }

// f32 -> bf16 bits, round-to-nearest-even
__device__ __forceinline__ unsigned short f2b(float f) {
    unsigned u = __float_as_uint(f);
    unsigned r = u + 0x7FFFu + ((u >> 16) & 1u);
    return (unsigned short)(r >> 16);
}

// swizzled LDS index (ushort units) for [row][32] tiles, 8-elem granularity
__device__ __forceinline__ int swz(int row, int kg) {
    return row * 32 + (kg ^ ((row >> 1) & 3)) * 8;
}

// ---------------- fill ----------------
__global__ void fill_i32(int* __restrict__ p, int v, long n) {
    long i = (long)blockIdx.x * blockDim.x + threadIdx.x;
    long st = (long)gridDim.x * blockDim.x;
    for (; i < n; i += st) p[i] = v;
}

// ---------------- CSR build ----------------
__global__ void hist_kernel(const int* __restrict__ ed, int* __restrict__ deg, int E) {
    int e = blockIdx.x * blockDim.x + threadIdx.x;
    if (e < E) atomicAdd(&deg[ed[e]], 1);
}

#define SCAN_T 256
#define SCAN_E 16
// exclusive scan, level 1: 4096 elements per block
__global__ void __launch_bounds__(SCAN_T) scan1_kernel(
    const int* __restrict__ deg, int* __restrict__ off,
    int* __restrict__ bsum, int n)
{
    __shared__ int lds[SCAN_T];
    const int tb = blockIdx.x * (SCAN_T * SCAN_E) + threadIdx.x * SCAN_E;
    int v[SCAN_E];
    int tot = 0;
#pragma unroll
    for (int j = 0; j < SCAN_E; ++j) {
        v[j] = (tb + j < n) ? deg[tb + j] : 0;
        tot += v[j];
    }
    lds[threadIdx.x] = tot;
    __syncthreads();
    for (int s = 1; s < SCAN_T; s <<= 1) {
        int t = (threadIdx.x >= s) ? lds[threadIdx.x - s] : 0;
        __syncthreads();
        lds[threadIdx.x] += t;
        __syncthreads();
    }
    int run = (threadIdx.x > 0) ? lds[threadIdx.x - 1] : 0;
#pragma unroll
    for (int j = 0; j < SCAN_E; ++j) {
        if (tb + j < n) off[tb + j] = run;
        run += v[j];
    }
    if (threadIdx.x == SCAN_T - 1) bsum[blockIdx.x] = lds[SCAN_T - 1];
}
// level 2: single-wave exclusive scan of block sums (nb <= 64)
__global__ void scan2_kernel(int* __restrict__ bsum, int nb) {
    int t = threadIdx.x;
    int orig = (t < nb) ? bsum[t] : 0;
    int v = orig;
    for (int s = 1; s < 64; s <<= 1) {
        int u = __shfl_up(v, s);
        if (t >= s) v += u;
    }
    if (t < nb) bsum[t] = v - orig;
}
// level 3: add block offsets
__global__ void scan3_kernel(int* __restrict__ off, const int* __restrict__ bsum, int n) {
    int i = blockIdx.x * blockDim.x + threadIdx.x;
    if (i < n) off[i] += bsum[i / (SCAN_T * SCAN_E)];
}

// bucket fill: rec[pos] = {src, bits(ea)}
__global__ void csr_fill_kernel(
    const int* __restrict__ es, const int* __restrict__ ed,
    const float* __restrict__ ea, const int* __restrict__ off,
    int* __restrict__ cur, int2* __restrict__ rec, int E)
{
    int e = blockIdx.x * blockDim.x + threadIdx.x;
    if (e >= E) return;
    int d = ed[e];
    int r = atomicAdd(&cur[d], 1);
    int2 q; q.x = es[e]; q.y = __float_as_int(ea[e]);
    rec[off[d] + r] = q;
}

// ---------------- weight transpose+convert: W[K][N] f32 -> Wt[N][K] bf16 ----
struct TxArgs {
    const float* src[10];
    unsigned short* dst[10];
    int K[10];
    int N[10];
};
__global__ void txp_kernel(TxArgs a) {
    const int m = blockIdx.y;
    const int K = a.K[m], N = a.N[m];
    const long total = (long)K * N;
    const float* __restrict__ s = a.src[m];
    unsigned short* __restrict__ d = a.dst[m];
    for (long i = (long)blockIdx.x * blockDim.x + threadIdx.x; i < total;
         i += (long)gridDim.x * blockDim.x) {
        int k = (int)(i / N), nn = (int)(i - (long)k * N);
        d[(long)nn * K + k] = f2b(s[i]);
    }
}

// ---------------- MFMA GEMM: Y[n,N](bf16) = A[n,K] @ W[K,N] + bias ----------
template<int K, int N, bool GATHER>
__global__ void __launch_bounds__(256) gemm_kernel(
    const void* __restrict__ Asrc, const int* __restrict__ ids,
    const unsigned short* __restrict__ Wt, const float* __restrict__ bias,
    unsigned short* __restrict__ Y, int n)
{
    constexpr int NCT = N / 64;
    const int t = threadIdx.x;
    const int wid = t >> 6, lane = t & 63;
    const int row0 = blockIdx.x * 64;

    __shared__ unsigned short As[64 * 32];
    __shared__ unsigned short Ws[N * 32];

    f32x4v acc[4][NCT];
#pragma unroll
    for (int rt = 0; rt < 4; ++rt)
#pragma unroll
        for (int ct = 0; ct < NCT; ++ct) acc[rt][ct] = (f32x4v){0.f, 0.f, 0.f, 0.f};

    const int r_st = t >> 2, kg_st = t & 3;
    const int grow = row0 + r_st;
    long abase = 0;
    if (grow < n) abase = GATHER ? (long)ids[grow] * K : (long)grow * K;

    for (int kt = 0; kt < K / 32; ++kt) {
        usht8 av = (usht8)0;
        if (grow < n) {
            if (GATHER) {
                const float* p = (const float*)Asrc + abase + kt * 32 + kg_st * 8;
#pragma unroll
                for (int j = 0; j < 8; ++j) av[j] = f2b(p[j]);
            } else {
                av = *(const usht8*)((const unsigned short*)Asrc + abase + kt * 32 + kg_st * 8);
            }
        }
        *(usht8*)&As[swz(r_st, kg_st)] = av;
#pragma unroll
        for (int i = 0; i < NCT; ++i) {
            int idx = t + i * 256;
            int c = idx >> 2, kg = idx & 3;
            *(usht8*)&Ws[swz(c, kg)] = *(const usht8*)&Wt[(long)c * K + kt * 32 + kg * 8];
        }
        __syncthreads();

        const int kgrp = lane >> 4;
        short8 af[4];
#pragma unroll
        for (int rt = 0; rt < 4; ++rt)
            af[rt] = *(const short8*)&As[swz(rt * 16 + (lane & 15), kgrp)];
#pragma unroll
        for (int ct = 0; ct < NCT; ++ct) {
            int col = wid * (N / 4) + ct * 16 + (lane & 15);
            short8 bfr = *(const short8*)&Ws[swz(col, kgrp)];
#pragma unroll
            for (int rt = 0; rt < 4; ++rt)
                acc[rt][ct] = __builtin_amdgcn_mfma_f32_16x16x32_bf16(af[rt], bfr, acc[rt][ct], 0, 0, 0);
        }
        __syncthreads();
    }

#pragma unroll
    for (int ct = 0; ct < NCT; ++ct) {
        int col = wid * (N / 4) + ct * 16 + (lane & 15);
        float bb = bias[col];
#pragma unroll
        for (int rt = 0; rt < 4; ++rt) {
#pragma unroll
            for (int j = 0; j < 4; ++j) {
                int row = row0 + rt * 16 + (lane >> 4) * 4 + j;
                if (row < n) Y[(long)row * N + col] = f2b(acc[rt][ct][j] + bb);
            }
        }
    }
}

// ---------------- fused GATv2 layer: one wave per destination node ----------
// CSR gather + edge logits + online softmax + weighted accum + bias + LN + act
// layout: channel c = h*64 + lane, heads H=4, C=64
template<bool CONCAT>
__global__ void __launch_bounds__(256) gat_fused_kernel(
    const int* __restrict__ deg, const int* __restrict__ off,
    const int2* __restrict__ rec,
    const bf16* __restrict__ xl, const bf16* __restrict__ xr,
    const float* __restrict__ We, const float* __restrict__ att,
    const float* __restrict__ bias,
    const float* __restrict__ g, const float* __restrict__ be,
    void* __restrict__ yout, int n)
{
    const int lane = threadIdx.x & 63;
    const int d = blockIdx.x * 4 + (threadIdx.x >> 6);
    if (d >= n) return;

    float We4[4], att4[4], xr4[4];
#pragma unroll
    for (int h = 0; h < 4; ++h) {
        int c = h * 64 + lane;
        We4[h] = We[c];
        att4[h] = att[c];
        xr4[h] = toF(xr[(long)d * 256 + c]);
    }

    float m[4], den[4], acc[4];
#pragma unroll
    for (int h = 0; h < 4; ++h) { m[h] = -1e30f; den[h] = 0.f; acc[h] = 0.f; }

    const int dg = deg[d], o0 = off[d];
    for (int base = 0; base < dg; base += 64) {
        int2 r; r.x = 0; r.y = 0;
        if (base + lane < dg) r = rec[o0 + base + lane];
        int cnt = min(dg - base, 64);
        for (int j = 0; j < cnt; ++j) {
            int s = __shfl(r.x, j);
            float a = __int_as_float(__shfl(r.y, j));
            const bf16* __restrict__ xls = xl + (long)s * 256;
            float xv[4], t[4];
#pragma unroll
            for (int h = 0; h < 4; ++h) {
                xv[h] = toF(xls[h * 64 + lane]);
                t[h] = lrelu02(xv[h] + xr4[h] + a * We4[h]) * att4[h];
            }
            // butterfly sum over 64 lanes -> per-head logit in all lanes
#pragma unroll
            for (int st = 1; st < 64; st <<= 1) {
#pragma unroll
                for (int h = 0; h < 4; ++h) t[h] += __shfl_xor(t[h], st);
            }
            // online softmax update (wave-uniform branches)
#pragma unroll
            for (int h = 0; h < 4; ++h) {
                float l = t[h];
                if (l > m[h]) {
                    float sc = __expf(m[h] - l);
                    den[h] *= sc; acc[h] *= sc; m[h] = l;
                }
                float p = __expf(l - m[h]);
                den[h] += p;
                acc[h] += p * xv[h];
            }
        }
    }

    if (CONCAT) {
        float v[4], s1 = 0.f, s2 = 0.f;
#pragma unroll
        for (int h = 0; h < 4; ++h) {
            v[h] = acc[h] / (den[h] + 1e-16f) + bias[h * 64 + lane];
            s1 += v[h]; s2 += v[h] * v[h];
        }
#pragma unroll
        for (int st = 1; st < 64; st <<= 1) {
            s1 += __shfl_xor(s1, st);
            s2 += __shfl_xor(s2, st);
        }
        float mean = s1 * (1.f / 256.f);
        float var = s2 * (1.f / 256.f) - mean * mean;
        float rr = rsqrtf(var + 1e-5f);
        unsigned short* y = (unsigned short*)yout;
#pragma unroll
        for (int h = 0; h < 4; ++h) {
            int c = h * 64 + lane;
            float o = g[c] * (v[h] - mean) * rr + be[c];
            y[(long)d * 256 + c] = f2b(lrelu02(o));
        }
    } else {
        float v = 0.f;
#pragma unroll
        for (int h = 0; h < 4; ++h) v += acc[h] / (den[h] + 1e-16f);
        v = 0.25f * v + bias[lane];
        float s1 = v, s2 = v * v;
#pragma unroll
        for (int st = 1; st < 64; st <<= 1) {
            s1 += __shfl_xor(s1, st);
            s2 += __shfl_xor(s2, st);
        }
        float mean = s1 * (1.f / 64.f);
        float var = s2 * (1.f / 64.f) - mean * mean;
        float rr = rsqrtf(var + 1e-5f);
        float o = g[lane] * (v - mean) * rr + be[lane];
        ((float*)yout)[(long)d * 64 + lane] = lrelu02(o);
    }
}

// ---------------- host orchestration ----------------
extern "C" void kernel_launch(void* const* d_in, const int* in_sizes, int n_in,
                              void* d_out, int out_size, void* d_ws, size_t ws_size,
                              hipStream_t stream)
{
    auto F = [&](int i) { return (const float*)d_in[i]; };
    auto I = [&](int i) { return (const int*)d_in[i]; };

    const int NU = in_sizes[0];
    const int NM = in_sizes[1];
    const int E  = in_sizes[2] / 2;

    const int* user_ids  = I(0);
    const int* movie_ids = I(1);
    const int* ei_um = I(2);
    const int* ei_mu = I(3);
    const float* ea_um = F(4);
    const float* ea_mu = F(5);
    const float* user_emb  = F(6);
    const float* movie_emb = F(7);
    const float* W_user = F(8),  *b_user = F(9);
    const float* W_movie = F(10), *b_movie = F(11);
    const int L0UM = 12, L0MU = 19, L1UM = 26, L1MU = 33;
    const float* g0u = F(40), *be0u = F(41);
    const float* g0m = F(42), *be0m = F(43);
    const float* g1u = F(44), *be1u = F(45);
    const float* g1m = F(46), *be1m = F(47);

    // ---- workspace layout ----
    char* w = (char*)d_ws;
    size_t off = 0;
    auto alloc = [&](size_t bytes) -> void* {
        void* p = w + off;
        off = (off + bytes + 255) & ~(size_t)255;
        return p;
    };
    bf16* UB1 = (bf16*)alloc((size_t)NU * 256 * 2);
    bf16* UB2 = (bf16*)alloc((size_t)NU * 256 * 2);
    bf16* MB1 = (bf16*)alloc((size_t)NM * 256 * 2);
    bf16* MB2 = (bf16*)alloc((size_t)NM * 256 * 2);
    bf16* MB3 = (bf16*)alloc((size_t)NM * 256 * 2);
    unsigned short* xu0b = (unsigned short*)alloc((size_t)NU * 64 * 2);
    unsigned short* xm0b = (unsigned short*)alloc((size_t)NM * 64 * 2);
    // CSR (dst = movies for um, dst = users for mu)
    int* deg_m = (int*)alloc((size_t)NM * 4);
    int* off_m = (int*)alloc((size_t)NM * 4);
    int* cur_m = (int*)alloc((size_t)NM * 4);
    int2* rec_m = (int2*)alloc((size_t)E * 8);
    int* deg_u = (int*)alloc((size_t)NU * 4);
    int* off_u = (int*)alloc((size_t)NU * 4);
    int* cur_u = (int*)alloc((size_t)NU * 4);
    int2* rec_u = (int2*)alloc((size_t)E * 8);
    int* bsum = (int*)alloc(64 * 4);
    // bf16 transposed weights
    unsigned short* wt_user   = (unsigned short*)alloc(64 * 64 * 2);
    unsigned short* wt_movie  = (unsigned short*)alloc(64 * 64 * 2);
    unsigned short* wt_l0um_l = (unsigned short*)alloc(64 * 256 * 2);
    unsigned short* wt_l0um_r = (unsigned short*)alloc(64 * 256 * 2);
    unsigned short* wt_l0mu_l = (unsigned short*)alloc(64 * 256 * 2);
    unsigned short* wt_l0mu_r = (unsigned short*)alloc(64 * 256 * 2);
    unsigned short* wt_l1um_l = (unsigned short*)alloc(256 * 256 * 2);
    unsigned short* wt_l1um_r = (unsigned short*)alloc(256 * 256 * 2);
    unsigned short* wt_l1mu_l = (unsigned short*)alloc(256 * 256 * 2);
    unsigned short* wt_l1mu_r = (unsigned short*)alloc(256 * 256 * 2);
    if (off > ws_size) return;

    float* out_u = (float*)d_out;
    float* out_m = out_u + (size_t)NU * 64;

    const int FB = 256;

    // ---- weight conversion ----
    TxArgs tx;
    const float* srcs[10] = {W_user, W_movie, F(L0UM+0), F(L0UM+2), F(L0MU+0), F(L0MU+2),
                             F(L1UM+0), F(L1UM+2), F(L1MU+0), F(L1MU+2)};
    unsigned short* dsts[10] = {wt_user, wt_movie, wt_l0um_l, wt_l0um_r, wt_l0mu_l, wt_l0mu_r,
                                wt_l1um_l, wt_l1um_r, wt_l1mu_l, wt_l1mu_r};
    int Ks[10] = {64, 64, 64, 64, 64, 64, 256, 256, 256, 256};
    int Ns[10] = {64, 64, 256, 256, 256, 256, 256, 256, 256, 256};
    for (int i = 0; i < 10; ++i) { tx.src[i] = srcs[i]; tx.dst[i] = dsts[i]; tx.K[i] = Ks[i]; tx.N[i] = Ns[i]; }
    txp_kernel<<<dim3(64, 10), 256, 0, stream>>>(tx);

    // ---- CSR build: um (dst = movies) ----
    fill_i32<<<CDIV(NM, FB), FB, 0, stream>>>(deg_m, 0, NM);
    hist_kernel<<<CDIV(E, FB), FB, 0, stream>>>(ei_um + E, deg_m, E);
    scan1_kernel<<<CDIV(NM, SCAN_T * SCAN_E), SCAN_T, 0, stream>>>(deg_m, off_m, bsum, NM);
    scan2_kernel<<<1, 64, 0, stream>>>(bsum, CDIV(NM, SCAN_T * SCAN_E));
    scan3_kernel<<<CDIV(NM, FB), FB, 0, stream>>>(off_m, bsum, NM);
    fill_i32<<<CDIV(NM, FB), FB, 0, stream>>>(cur_m, 0, NM);
    csr_fill_kernel<<<CDIV(E, FB), FB, 0, stream>>>(ei_um, ei_um + E, ea_um, off_m, cur_m, rec_m, E);

    // ---- CSR build: mu (dst = users) ----
    fill_i32<<<CDIV(NU, FB), FB, 0, stream>>>(deg_u, 0, NU);
    hist_kernel<<<CDIV(E, FB), FB, 0, stream>>>(ei_mu + E, deg_u, E);
    scan1_kernel<<<CDIV(NU, SCAN_T * SCAN_E), SCAN_T, 0, stream>>>(deg_u, off_u, bsum, NU);
    scan2_kernel<<<1, 64, 0, stream>>>(bsum, CDIV(NU, SCAN_T * SCAN_E));
    scan3_kernel<<<CDIV(NU, FB), FB, 0, stream>>>(off_u, bsum, NU);
    fill_i32<<<CDIV(NU, FB), FB, 0, stream>>>(cur_u, 0, NU);
    csr_fill_kernel<<<CDIV(E, FB), FB, 0, stream>>>(ei_mu, ei_mu + E, ea_mu, off_u, cur_u, rec_u, E);

    // ---- phase 0: embedding gather + input projection (MFMA) ----
    gemm_kernel<64, 64, true><<<CDIV(NU, 64), 256, 0, stream>>>(user_emb, user_ids, wt_user, b_user, xu0b, NU);
    gemm_kernel<64, 64, true><<<CDIV(NM, 64), 256, 0, stream>>>(movie_emb, movie_ids, wt_movie, b_movie, xm0b, NM);

    // ---- layer-0 projections ----
    gemm_kernel<64, 256, false><<<CDIV(NU, 64), 256, 0, stream>>>(xu0b, nullptr, wt_l0um_l, F(L0UM+1), (unsigned short*)UB1, NU); // xl_u0
    gemm_kernel<64, 256, false><<<CDIV(NM, 64), 256, 0, stream>>>(xm0b, nullptr, wt_l0um_r, F(L0UM+3), (unsigned short*)MB1, NM); // xr_m0
    gemm_kernel<64, 256, false><<<CDIV(NM, 64), 256, 0, stream>>>(xm0b, nullptr, wt_l0mu_l, F(L0MU+1), (unsigned short*)MB3, NM); // xl_m0
    gemm_kernel<64, 256, false><<<CDIV(NU, 64), 256, 0, stream>>>(xu0b, nullptr, wt_l0mu_r, F(L0MU+3), (unsigned short*)UB2, NU); // xr_u0

    // ---- layer 0 fused GAT ----
    // um: dst=movies -> xm1 in MB2
    gat_fused_kernel<true><<<CDIV(NM, 4), 256, 0, stream>>>(
        deg_m, off_m, rec_m, UB1, MB1, F(L0UM+4), F(L0UM+5), F(L0UM+6), g0m, be0m, MB2, NM);
    // mu: dst=users -> xu1 in UB1 (UB1 dead after um pass)
    gat_fused_kernel<true><<<CDIV(NU, 4), 256, 0, stream>>>(
        deg_u, off_u, rec_u, MB3, UB2, F(L0MU+4), F(L0MU+5), F(L0MU+6), g0u, be0u, UB1, NU);

    // ---- layer-1 projections ----
    gemm_kernel<256, 256, false><<<CDIV(NU, 64), 256, 0, stream>>>((unsigned short*)UB1, nullptr, wt_l1um_l, F(L1UM+1), (unsigned short*)UB2, NU); // xl_u1
    gemm_kernel<256, 256, false><<<CDIV(NM, 64), 256, 0, stream>>>((unsigned short*)MB2, nullptr, wt_l1um_r, F(L1UM+3), (unsigned short*)MB1, NM); // xr_m1
    // um: dst=movies -> out_m (f32) with LN
    gat_fused_kernel<false><<<CDIV(NM, 4), 256, 0, stream>>>(
        deg_m, off_m, rec_m, UB2, MB1, F(L1UM+4), F(L1UM+5), F(L1UM+6), g1m, be1m, out_m, NM);

    gemm_kernel<256, 256, false><<<CDIV(NM, 64), 256, 0, stream>>>((unsigned short*)MB2, nullptr, wt_l1mu_l, F(L1MU+1), (unsigned short*)MB3, NM); // xl_m1
    gemm_kernel<256, 256, false><<<CDIV(NU, 64), 256, 0, stream>>>((unsigned short*)UB1, nullptr, wt_l1mu_r, F(L1MU+3), (unsigned short*)UB2, NU); // xr_u1
    // mu: dst=users -> out_u (f32) with LN
    gat_fused_kernel<false><<<CDIV(NU, 4), 256, 0, stream>>>(
        deg_u, off_u, rec_u, MB3, UB2, F(L1MU+4), F(L1MU+5), F(L1MU+6), g1u, be1u, out_u, NU);
}

// Round 5
// 576.704 us; speedup vs baseline: 3.5496x; 1.3035x over previous
//
#include <hip/hip_runtime.h>
#include <hip/hip_bf16.h>
#include <cstdint>

typedef __hip_bfloat16 bf16;
#define CDIV(a,b) (((a)+(b)-1)/(b))

typedef __attribute__((ext_vector_type(8))) short short8;
typedef __attribute__((ext_vector_type(8))) unsigned short usht8;
typedef __attribute__((ext_vector_type(4))) float f32x4v;

struct us4 { unsigned short x, y, z, w; };

// ---------------- device helpers ----------------
__device__ __forceinline__ float lrelu02(float x) { return fmaxf(x, 0.f) + 0.2f * fminf(x, 0.f); }

__device__ __forceinline__ float toF(float x) { return x; }
__device__ __forceinline__ float toF(bf16 x) { return __bfloat162float(x); }

__device__ __forceinline__ float b2f(unsigned short u) {
    return __uint_as_float((unsigned)u << 16);
}
// f32 -> bf16 bits, round-to-nearest-even
__device__ __forceinline__ unsigned short f2b(float f) {
    unsigned u = __float_as_uint(f);
    unsigned r = u + 0x7FFFu + ((u >> 16) & 1u);
    return (unsigned short)(r >> 16);
}

// swizzled LDS index (ushort units) for [row][32] tiles, 8-elem granularity
__device__ __forceinline__ int swz(int row, int kg) {
    return row * 32 + (kg ^ ((row >> 1) & 3)) * 8;
}

// ---------------- fill ----------------
__global__ void fill_i32(int* __restrict__ p, int v, long n) {
    long i = (long)blockIdx.x * blockDim.x + threadIdx.x;
    long st = (long)gridDim.x * blockDim.x;
    for (; i < n; i += st) p[i] = v;
}

// ---------------- CSR build ----------------
__global__ void hist_kernel(const int* __restrict__ ed, int* __restrict__ deg, int E) {
    int e = blockIdx.x * blockDim.x + threadIdx.x;
    if (e < E) atomicAdd(&deg[ed[e]], 1);
}

#define SCAN_T 256
#define SCAN_E 16
__global__ void __launch_bounds__(SCAN_T) scan1_kernel(
    const int* __restrict__ deg, int* __restrict__ off,
    int* __restrict__ bsum, int n)
{
    __shared__ int lds[SCAN_T];
    const int tb = blockIdx.x * (SCAN_T * SCAN_E) + threadIdx.x * SCAN_E;
    int v[SCAN_E];
    int tot = 0;
#pragma unroll
    for (int j = 0; j < SCAN_E; ++j) {
        v[j] = (tb + j < n) ? deg[tb + j] : 0;
        tot += v[j];
    }
    lds[threadIdx.x] = tot;
    __syncthreads();
    for (int s = 1; s < SCAN_T; s <<= 1) {
        int t = (threadIdx.x >= s) ? lds[threadIdx.x - s] : 0;
        __syncthreads();
        lds[threadIdx.x] += t;
        __syncthreads();
    }
    int run = (threadIdx.x > 0) ? lds[threadIdx.x - 1] : 0;
#pragma unroll
    for (int j = 0; j < SCAN_E; ++j) {
        if (tb + j < n) off[tb + j] = run;
        run += v[j];
    }
    if (threadIdx.x == SCAN_T - 1) bsum[blockIdx.x] = lds[SCAN_T - 1];
}
__global__ void scan2_kernel(int* __restrict__ bsum, int nb) {
    int t = threadIdx.x;
    int orig = (t < nb) ? bsum[t] : 0;
    int v = orig;
    for (int s = 1; s < 64; s <<= 1) {
        int u = __shfl_up(v, s);
        if (t >= s) v += u;
    }
    if (t < nb) bsum[t] = v - orig;
}
__global__ void scan3_kernel(int* __restrict__ off, const int* __restrict__ bsum, int n) {
    int i = blockIdx.x * blockDim.x + threadIdx.x;
    if (i < n) off[i] += bsum[i / (SCAN_T * SCAN_E)];
}

__global__ void csr_fill_kernel(
    const int* __restrict__ es, const int* __restrict__ ed,
    const float* __restrict__ ea, const int* __restrict__ off,
    int* __restrict__ cur, int2* __restrict__ rec, int E)
{
    int e = blockIdx.x * blockDim.x + threadIdx.x;
    if (e >= E) return;
    int d = ed[e];
    int r = atomicAdd(&cur[d], 1);
    int2 q; q.x = es[e]; q.y = __float_as_int(ea[e]);
    rec[off[d] + r] = q;
}

// ---------------- weight transpose+convert ----------------
struct TxArgs {
    const float* src[10];
    unsigned short* dst[10];
    int K[10];
    int N[10];
};
__global__ void txp_kernel(TxArgs a) {
    const int m = blockIdx.y;
    const int K = a.K[m], N = a.N[m];
    const long total = (long)K * N;
    const float* __restrict__ s = a.src[m];
    unsigned short* __restrict__ d = a.dst[m];
    for (long i = (long)blockIdx.x * blockDim.x + threadIdx.x; i < total;
         i += (long)gridDim.x * blockDim.x) {
        int k = (int)(i / N), nn = (int)(i - (long)k * N);
        d[(long)nn * K + k] = f2b(s[i]);
    }
}

// ---------------- MFMA GEMM ----------------
template<int K, int N, bool GATHER>
__global__ void __launch_bounds__(256) gemm_kernel(
    const void* __restrict__ Asrc, const int* __restrict__ ids,
    const unsigned short* __restrict__ Wt, const float* __restrict__ bias,
    unsigned short* __restrict__ Y, int n)
{
    constexpr int NCT = N / 64;
    const int t = threadIdx.x;
    const int wid = t >> 6, lane = t & 63;
    const int row0 = blockIdx.x * 64;

    __shared__ unsigned short As[64 * 32];
    __shared__ unsigned short Ws[N * 32];

    f32x4v acc[4][NCT];
#pragma unroll
    for (int rt = 0; rt < 4; ++rt)
#pragma unroll
        for (int ct = 0; ct < NCT; ++ct) acc[rt][ct] = (f32x4v){0.f, 0.f, 0.f, 0.f};

    const int r_st = t >> 2, kg_st = t & 3;
    const int grow = row0 + r_st;
    long abase = 0;
    if (grow < n) abase = GATHER ? (long)ids[grow] * K : (long)grow * K;

    for (int kt = 0; kt < K / 32; ++kt) {
        usht8 av = (usht8)0;
        if (grow < n) {
            if (GATHER) {
                const float* p = (const float*)Asrc + abase + kt * 32 + kg_st * 8;
#pragma unroll
                for (int j = 0; j < 8; ++j) av[j] = f2b(p[j]);
            } else {
                av = *(const usht8*)((const unsigned short*)Asrc + abase + kt * 32 + kg_st * 8);
            }
        }
        *(usht8*)&As[swz(r_st, kg_st)] = av;
#pragma unroll
        for (int i = 0; i < NCT; ++i) {
            int idx = t + i * 256;
            int c = idx >> 2, kg = idx & 3;
            *(usht8*)&Ws[swz(c, kg)] = *(const usht8*)&Wt[(long)c * K + kt * 32 + kg * 8];
        }
        __syncthreads();

        const int kgrp = lane >> 4;
        short8 af[4];
#pragma unroll
        for (int rt = 0; rt < 4; ++rt)
            af[rt] = *(const short8*)&As[swz(rt * 16 + (lane & 15), kgrp)];
#pragma unroll
        for (int ct = 0; ct < NCT; ++ct) {
            int col = wid * (N / 4) + ct * 16 + (lane & 15);
            short8 bfr = *(const short8*)&Ws[swz(col, kgrp)];
#pragma unroll
            for (int rt = 0; rt < 4; ++rt)
                acc[rt][ct] = __builtin_amdgcn_mfma_f32_16x16x32_bf16(af[rt], bfr, acc[rt][ct], 0, 0, 0);
        }
        __syncthreads();
    }

#pragma unroll
    for (int ct = 0; ct < NCT; ++ct) {
        int col = wid * (N / 4) + ct * 16 + (lane & 15);
        float bb = bias[col];
#pragma unroll
        for (int rt = 0; rt < 4; ++rt) {
#pragma unroll
            for (int j = 0; j < 4; ++j) {
                int row = row0 + rt * 16 + (lane >> 4) * 4 + j;
                if (row < n) Y[(long)row * N + col] = f2b(acc[rt][ct][j] + bb);
            }
        }
    }
}

// ---------------- fused GATv2 layer (head-split lanes) ----------------
// lane = h*16 + q; lane owns channels c = h*64 + q*4 .. +3
// one wave per destination; 4-edge batches for load ILP; branchless online softmax
template<bool CONCAT>
__global__ void __launch_bounds__(256) gat_fused_kernel(
    const int* __restrict__ deg, const int* __restrict__ off,
    const int2* __restrict__ rec,
    const bf16* __restrict__ xl, const bf16* __restrict__ xr,
    const float* __restrict__ We, const float* __restrict__ att,
    const float* __restrict__ bias,
    const float* __restrict__ g, const float* __restrict__ be,
    void* __restrict__ yout, int n)
{
    const int lane = threadIdx.x & 63;
    const int d = blockIdx.x * 4 + (threadIdx.x >> 6);
    if (d >= n) return;
    const int q = lane & 15;
    const int c0 = ((lane >> 4) << 6) + (q << 2);   // h*64 + q*4

    float4 We4 = *(const float4*)(We + c0);
    float4 att4 = *(const float4*)(att + c0);
    us4 xrv = *(const us4*)((const unsigned short*)xr + (long)d * 256 + c0);
    float xr4[4] = {b2f(xrv.x), b2f(xrv.y), b2f(xrv.z), b2f(xrv.w)};

    float m = -1e30f, den = 0.f;
    float acc[4] = {0.f, 0.f, 0.f, 0.f};

    const int dg = deg[d], o0 = off[d];
    const unsigned short* __restrict__ xlp = (const unsigned short*)xl;

    for (int base = 0; base < dg; base += 64) {
        int2 r;
        if (base + lane < dg) r = rec[o0 + base + lane];
        else { r.x = 0; r.y = 0; }
        const int cnt = min(dg - base, 64);
        for (int j = 0; j < cnt; j += 4) {
            int sA[4]; float aA[4]; us4 xvA[4];
#pragma unroll
            for (int u = 0; u < 4; ++u) {
                sA[u] = __shfl(r.x, j + u);
                aA[u] = __int_as_float(__shfl(r.y, j + u));
            }
#pragma unroll
            for (int u = 0; u < 4; ++u)
                xvA[u] = *(const us4*)(xlp + (long)sA[u] * 256 + c0);
#pragma unroll
            for (int u = 0; u < 4; ++u) {
                float xv[4] = {b2f(xvA[u].x), b2f(xvA[u].y), b2f(xvA[u].z), b2f(xvA[u].w)};
                float part = 0.f;
#pragma unroll
                for (int i = 0; i < 4; ++i) {
                    float t = xv[i] + fmaf(aA[u], (&We4.x)[i], xr4[i]);
                    part = fmaf(lrelu02(t), (&att4.x)[i], part);
                }
                // reduce over the 16-lane head group (all 4 heads in parallel)
#pragma unroll
                for (int st = 1; st < 16; st <<= 1) part += __shfl_xor(part, st);
                float l = (j + u < cnt) ? part : -1e30f;
                float mn = fmaxf(m, l);
                float sc = __expf(m - mn);
                float p  = __expf(l - mn);
                m = mn;
                den = fmaf(den, sc, p);
#pragma unroll
                for (int i = 0; i < 4; ++i) acc[i] = fmaf(acc[i], sc, p * xv[i]);
            }
        }
    }

    const float id = 1.f / (den + 1e-16f);
    if (CONCAT) {
        float4 bi = *(const float4*)(bias + c0);
        float v[4], s1 = 0.f, s2 = 0.f;
#pragma unroll
        for (int i = 0; i < 4; ++i) {
            v[i] = fmaf(acc[i], id, (&bi.x)[i]);
            s1 += v[i]; s2 = fmaf(v[i], v[i], s2);
        }
#pragma unroll
        for (int st = 1; st < 64; st <<= 1) {
            s1 += __shfl_xor(s1, st);
            s2 += __shfl_xor(s2, st);
        }
        float mean = s1 * (1.f / 256.f);
        float var = s2 * (1.f / 256.f) - mean * mean;
        float rr = rsqrtf(var + 1e-5f);
        float4 gg = *(const float4*)(g + c0);
        float4 bb = *(const float4*)(be + c0);
        us4 o;
        o.x = f2b(lrelu02(fmaf((&gg.x)[0] * rr, v[0] - mean, (&bb.x)[0])));
        o.y = f2b(lrelu02(fmaf((&gg.x)[1] * rr, v[1] - mean, (&bb.x)[1])));
        o.z = f2b(lrelu02(fmaf((&gg.x)[2] * rr, v[2] - mean, (&bb.x)[2])));
        o.w = f2b(lrelu02(fmaf((&gg.x)[3] * rr, v[3] - mean, (&bb.x)[3])));
        *(us4*)((unsigned short*)yout + (long)d * 256 + c0) = o;
    } else {
        float vh[4];
#pragma unroll
        for (int i = 0; i < 4; ++i) vh[i] = acc[i] * id;
        // sum over the 4 head groups (lanes differing in bits 4,5)
#pragma unroll
        for (int st = 16; st < 64; st <<= 1)
#pragma unroll
            for (int i = 0; i < 4; ++i) vh[i] += __shfl_xor(vh[i], st);
        const int oc = q << 2;
        float4 bi = *(const float4*)(bias + oc);
        float v[4], s1 = 0.f, s2 = 0.f;
#pragma unroll
        for (int i = 0; i < 4; ++i) {
            v[i] = fmaf(0.25f, vh[i], (&bi.x)[i]);
            s1 += v[i]; s2 = fmaf(v[i], v[i], s2);
        }
#pragma unroll
        for (int st = 1; st < 16; st <<= 1) {
            s1 += __shfl_xor(s1, st);
            s2 += __shfl_xor(s2, st);
        }
        float mean = s1 * (1.f / 64.f);
        float var = s2 * (1.f / 64.f) - mean * mean;
        float rr = rsqrtf(var + 1e-5f);
        float4 gg = *(const float4*)(g + oc);
        float4 bb = *(const float4*)(be + oc);
        if (lane < 16) {
            float4 o;
            o.x = lrelu02(fmaf((&gg.x)[0] * rr, v[0] - mean, (&bb.x)[0]));
            o.y = lrelu02(fmaf((&gg.x)[1] * rr, v[1] - mean, (&bb.x)[1]));
            o.z = lrelu02(fmaf((&gg.x)[2] * rr, v[2] - mean, (&bb.x)[2]));
            o.w = lrelu02(fmaf((&gg.x)[3] * rr, v[3] - mean, (&bb.x)[3]));
            *(float4*)((float*)yout + (long)d * 64 + oc) = o;
        }
    }
}

// ---------------- host orchestration ----------------
extern "C" void kernel_launch(void* const* d_in, const int* in_sizes, int n_in,
                              void* d_out, int out_size, void* d_ws, size_t ws_size,
                              hipStream_t stream)
{
    auto F = [&](int i) { return (const float*)d_in[i]; };
    auto I = [&](int i) { return (const int*)d_in[i]; };

    const int NU = in_sizes[0];
    const int NM = in_sizes[1];
    const int E  = in_sizes[2] / 2;

    const int* user_ids  = I(0);
    const int* movie_ids = I(1);
    const int* ei_um = I(2);
    const int* ei_mu = I(3);
    const float* ea_um = F(4);
    const float* ea_mu = F(5);
    const float* user_emb  = F(6);
    const float* movie_emb = F(7);
    const float* W_user = F(8),  *b_user = F(9);
    const float* W_movie = F(10), *b_movie = F(11);
    const int L0UM = 12, L0MU = 19, L1UM = 26, L1MU = 33;
    const float* g0u = F(40), *be0u = F(41);
    const float* g0m = F(42), *be0m = F(43);
    const float* g1u = F(44), *be1u = F(45);
    const float* g1m = F(46), *be1m = F(47);

    // ---- workspace layout ----
    char* w = (char*)d_ws;
    size_t off = 0;
    auto alloc = [&](size_t bytes) -> void* {
        void* p = w + off;
        off = (off + bytes + 255) & ~(size_t)255;
        return p;
    };
    bf16* UB1 = (bf16*)alloc((size_t)NU * 256 * 2);
    bf16* UB2 = (bf16*)alloc((size_t)NU * 256 * 2);
    bf16* MB1 = (bf16*)alloc((size_t)NM * 256 * 2);
    bf16* MB2 = (bf16*)alloc((size_t)NM * 256 * 2);
    bf16* MB3 = (bf16*)alloc((size_t)NM * 256 * 2);
    unsigned short* xu0b = (unsigned short*)alloc((size_t)NU * 64 * 2);
    unsigned short* xm0b = (unsigned short*)alloc((size_t)NM * 64 * 2);
    int* deg_m = (int*)alloc((size_t)NM * 4);
    int* off_m = (int*)alloc((size_t)NM * 4);
    int* cur_m = (int*)alloc((size_t)NM * 4);
    int2* rec_m = (int2*)alloc((size_t)E * 8);
    int* deg_u = (int*)alloc((size_t)NU * 4);
    int* off_u = (int*)alloc((size_t)NU * 4);
    int* cur_u = (int*)alloc((size_t)NU * 4);
    int2* rec_u = (int2*)alloc((size_t)E * 8);
    int* bsum = (int*)alloc(64 * 4);
    unsigned short* wt_user   = (unsigned short*)alloc(64 * 64 * 2);
    unsigned short* wt_movie  = (unsigned short*)alloc(64 * 64 * 2);
    unsigned short* wt_l0um_l = (unsigned short*)alloc(64 * 256 * 2);
    unsigned short* wt_l0um_r = (unsigned short*)alloc(64 * 256 * 2);
    unsigned short* wt_l0mu_l = (unsigned short*)alloc(64 * 256 * 2);
    unsigned short* wt_l0mu_r = (unsigned short*)alloc(64 * 256 * 2);
    unsigned short* wt_l1um_l = (unsigned short*)alloc(256 * 256 * 2);
    unsigned short* wt_l1um_r = (unsigned short*)alloc(256 * 256 * 2);
    unsigned short* wt_l1mu_l = (unsigned short*)alloc(256 * 256 * 2);
    unsigned short* wt_l1mu_r = (unsigned short*)alloc(256 * 256 * 2);
    if (off > ws_size) return;

    float* out_u = (float*)d_out;
    float* out_m = out_u + (size_t)NU * 64;

    const int FB = 256;

    // ---- weight conversion ----
    TxArgs tx;
    const float* srcs[10] = {W_user, W_movie, F(L0UM+0), F(L0UM+2), F(L0MU+0), F(L0MU+2),
                             F(L1UM+0), F(L1UM+2), F(L1MU+0), F(L1MU+2)};
    unsigned short* dsts[10] = {wt_user, wt_movie, wt_l0um_l, wt_l0um_r, wt_l0mu_l, wt_l0mu_r,
                                wt_l1um_l, wt_l1um_r, wt_l1mu_l, wt_l1mu_r};
    int Ks[10] = {64, 64, 64, 64, 64, 64, 256, 256, 256, 256};
    int Ns[10] = {64, 64, 256, 256, 256, 256, 256, 256, 256, 256};
    for (int i = 0; i < 10; ++i) { tx.src[i] = srcs[i]; tx.dst[i] = dsts[i]; tx.K[i] = Ks[i]; tx.N[i] = Ns[i]; }
    txp_kernel<<<dim3(64, 10), 256, 0, stream>>>(tx);

    // ---- CSR build: um (dst = movies) ----
    fill_i32<<<CDIV(NM, FB), FB, 0, stream>>>(deg_m, 0, NM);
    hist_kernel<<<CDIV(E, FB), FB, 0, stream>>>(ei_um + E, deg_m, E);
    scan1_kernel<<<CDIV(NM, SCAN_T * SCAN_E), SCAN_T, 0, stream>>>(deg_m, off_m, bsum, NM);
    scan2_kernel<<<1, 64, 0, stream>>>(bsum, CDIV(NM, SCAN_T * SCAN_E));
    scan3_kernel<<<CDIV(NM, FB), FB, 0, stream>>>(off_m, bsum, NM);
    fill_i32<<<CDIV(NM, FB), FB, 0, stream>>>(cur_m, 0, NM);
    csr_fill_kernel<<<CDIV(E, FB), FB, 0, stream>>>(ei_um, ei_um + E, ea_um, off_m, cur_m, rec_m, E);

    // ---- CSR build: mu (dst = users) ----
    fill_i32<<<CDIV(NU, FB), FB, 0, stream>>>(deg_u, 0, NU);
    hist_kernel<<<CDIV(E, FB), FB, 0, stream>>>(ei_mu + E, deg_u, E);
    scan1_kernel<<<CDIV(NU, SCAN_T * SCAN_E), SCAN_T, 0, stream>>>(deg_u, off_u, bsum, NU);
    scan2_kernel<<<1, 64, 0, stream>>>(bsum, CDIV(NU, SCAN_T * SCAN_E));
    scan3_kernel<<<CDIV(NU, FB), FB, 0, stream>>>(off_u, bsum, NU);
    fill_i32<<<CDIV(NU, FB), FB, 0, stream>>>(cur_u, 0, NU);
    csr_fill_kernel<<<CDIV(E, FB), FB, 0, stream>>>(ei_mu, ei_mu + E, ea_mu, off_u, cur_u, rec_u, E);

    // ---- phase 0: embedding gather + input projection (MFMA) ----
    gemm_kernel<64, 64, true><<<CDIV(NU, 64), 256, 0, stream>>>(user_emb, user_ids, wt_user, b_user, xu0b, NU);
    gemm_kernel<64, 64, true><<<CDIV(NM, 64), 256, 0, stream>>>(movie_emb, movie_ids, wt_movie, b_movie, xm0b, NM);

    // ---- layer-0 projections ----
    gemm_kernel<64, 256, false><<<CDIV(NU, 64), 256, 0, stream>>>(xu0b, nullptr, wt_l0um_l, F(L0UM+1), (unsigned short*)UB1, NU); // xl_u0
    gemm_kernel<64, 256, false><<<CDIV(NM, 64), 256, 0, stream>>>(xm0b, nullptr, wt_l0um_r, F(L0UM+3), (unsigned short*)MB1, NM); // xr_m0
    gemm_kernel<64, 256, false><<<CDIV(NM, 64), 256, 0, stream>>>(xm0b, nullptr, wt_l0mu_l, F(L0MU+1), (unsigned short*)MB3, NM); // xl_m0
    gemm_kernel<64, 256, false><<<CDIV(NU, 64), 256, 0, stream>>>(xu0b, nullptr, wt_l0mu_r, F(L0MU+3), (unsigned short*)UB2, NU); // xr_u0

    // ---- layer 0 fused GAT ----
    gat_fused_kernel<true><<<CDIV(NM, 4), 256, 0, stream>>>(
        deg_m, off_m, rec_m, UB1, MB1, F(L0UM+4), F(L0UM+5), F(L0UM+6), g0m, be0m, MB2, NM);
    gat_fused_kernel<true><<<CDIV(NU, 4), 256, 0, stream>>>(
        deg_u, off_u, rec_u, MB3, UB2, F(L0MU+4), F(L0MU+5), F(L0MU+6), g0u, be0u, UB1, NU);

    // ---- layer-1 projections + fused GAT ----
    gemm_kernel<256, 256, false><<<CDIV(NU, 64), 256, 0, stream>>>((unsigned short*)UB1, nullptr, wt_l1um_l, F(L1UM+1), (unsigned short*)UB2, NU); // xl_u1
    gemm_kernel<256, 256, false><<<CDIV(NM, 64), 256, 0, stream>>>((unsigned short*)MB2, nullptr, wt_l1um_r, F(L1UM+3), (unsigned short*)MB1, NM); // xr_m1
    gat_fused_kernel<false><<<CDIV(NM, 4), 256, 0, stream>>>(
        deg_m, off_m, rec_m, UB2, MB1, F(L1UM+4), F(L1UM+5), F(L1UM+6), g1m, be1m, out_m, NM);

    gemm_kernel<256, 256, false><<<CDIV(NM, 64), 256, 0, stream>>>((unsigned short*)MB2, nullptr, wt_l1mu_l, F(L1MU+1), (unsigned short*)MB3, NM); // xl_m1
    gemm_kernel<256, 256, false><<<CDIV(NU, 64), 256, 0, stream>>>((unsigned short*)UB1, nullptr, wt_l1mu_r, F(L1MU+3), (unsigned short*)UB2, NU); // xr_u1
    gat_fused_kernel<false><<<CDIV(NU, 4), 256, 0, stream>>>(
        deg_u, off_u, rec_u, MB3, UB2, F(L1MU+4), F(L1MU+5), F(L1MU+6), g1u, be1u, out_u, NU);
}